// Round 15
// baseline (877.566 us; speedup 1.0000x reference)
//
#include <hip/hip_runtime.h>
#include <math.h>
#include <type_traits>

// TVB MPR simulation + BOLD, v15: v13 machinery re-split into two 512-thread
// teams (1024 threads = 16 waves = 4/SIMD) to test the TLP/stall hypothesis.
//
//   Team A (tid 0..511, 4 lanes/region): j in [0,64). 16 pair-slots, 8
//     ds_read_b64/step (prefetched, refill LAST). Pooled lag<=2 singles
//     (3/lane, over the FULL row). Adds team B's pre-reduced bulk float
//     bB[(s+1)&1][i] (written by B at step s-1). MPR + ring/rv writes.
//   Team B (tid 512..1023, 4 lanes/region): j in [64,128), addresses one
//     time-unit ahead: pair at step s = (r(s+2-lag), r(s+3-lag)), times<=s.
//     Reduce4 -> leader writes bB[s&1][i] (bulk-B of c(s+2)). BOLD Heun
//     chains ride on B's quad-leaders (B has no MPR).
//   ONE raw (lgkmcnt-only) barrier per step; 65-unit dual-copy pair ring.
//
// Ring: 65 units x 2048 B; pair starting biased time T at (T*1024 + j*8)
// mod 133120. Reads at step s touch times <= s; write r(s+1) -> slot
// (s+1) mod 130, never aliasing [s-125, s]: race-free single phase.

namespace {
constexpr int NREG  = 128;
constexpr int NSTEP = 1000;
constexpr int UNITS = 65;
constexpr unsigned RING_BYTES = UNITS * 2048u;      // 133120
constexpr int RING_FLOATS = (int)(RING_BYTES / 4);  // 33280
constexpr int NSING = 12;                           // pool slots per region
constexpr int NTHR  = 1024;

__device__ __forceinline__ float fsqrt_raw(float x){ float r; asm("v_sqrt_f32 %0, %1" : "=v"(r) : "v"(x)); return r; }
__device__ __forceinline__ float frcp_raw (float x){ float r; asm("v_rcp_f32 %0, %1" : "=v"(r) : "v"(x)); return r; }
__device__ __forceinline__ float fexp2_raw(float x){ float r; asm("v_exp_f32 %0, %1" : "=v"(r) : "v"(x)); return r; }

__device__ __forceinline__ float pow3125(float v) {
    float s1 = fsqrt_raw(v);
    float s2 = fsqrt_raw(s1);
    float s3 = fsqrt_raw(s2);
    return v * v * v * s3;
}

__device__ __forceinline__ float dpp_add_xor1(float x){
    int y = __builtin_amdgcn_mov_dpp(__float_as_int(x), 0xB1, 0xF, 0xF, true); // [1,0,3,2]
    return x + __int_as_float(y);
}
__device__ __forceinline__ float dpp_add_xor2(float x){
    int y = __builtin_amdgcn_mov_dpp(__float_as_int(x), 0x4E, 0xF, 0xF, true); // [2,3,0,1]
    return x + __int_as_float(y);
}
__device__ __forceinline__ float reduce4(float x){
    return dpp_add_xor2(dpp_add_xor1(x));
}

// raw workgroup barrier: LDS drained, global ops keep flying (no vmcnt(0))
__device__ __forceinline__ void wg_barrier() {
    asm volatile("s_waitcnt lgkmcnt(0)" ::: "memory");
    __builtin_amdgcn_s_barrier();
    asm volatile("" ::: "memory");
}

// copyA dword byte-offset of time T on the 65-unit ring (valid T >= -260)
__device__ __forceinline__ unsigned rowOf(int T) {
    const unsigned Tb = (unsigned)(T + 260);        // parity-preserving bias
    return ((Tb >> 1) % UNITS) * 2048u + ((Tb & 1u) << 2);
}
} // namespace

__launch_bounds__(NTHR, 1)
__global__ void tvb_kernel(const float* __restrict__ region_pars,  // (128,1)
                           const float* __restrict__ Wt,           // (128,128,1)
                           const float* __restrict__ g,            // (1,)
                           const float* __restrict__ stimulus,     // (100,1)
                           const float* __restrict__ noise,        // (100,10,128,2)
                           const float* __restrict__ initial_cond, // (128,2)
                           const int*   __restrict__ lags,         // (128,128)
                           float* __restrict__ out)                // rv(1000,128,2) ++ bold(128)
{
    __shared__ float lds[RING_FLOATS];       // 130 KB pair ring
    __shared__ float sw[NREG * NSING];       // pool: weights
    __shared__ int   smeta[NREG * NSING];    // pool: (j<<3)|(lag-1)
    __shared__ int   cnt[NREG];              // pool fill counters
    __shared__ float bB[2][NREG];            // B bulk handoff (parity dbuf)
    __shared__ float bC0[NREG];              // B full r0 half-sum (c(0))
    char* histc = (char*)lds;

    const int tid = (int)threadIdx.x;
    const bool isA = tid < 512;
    const int i  = (tid >> 2) & 127;  // region (both teams)
    const int h  = tid & 3;

    // ---- constants ----
    constexpr float ONE_PI = (float)(1.0 / 3.14159265358979323846);
    constexpr float PI_F   = (float)3.14159265358979323846;
    constexpr float RTS    = (float)(1.0 / 0.65);
    constexpr float RTF    = (float)(1.0 / 0.41);
    constexpr float RTO    = (float)(1.0 / 0.98);
    constexpr float K1     = (float)(4.3 * 40.3 * 0.4 * 0.04);
    constexpr float K2     = (float)(0.5 * 25.0 * 0.4 * 0.04);
    constexpr float L06    = -0.7369655941662062f;                  // log2(0.6)
    const float DWS = 0.01f * sqrtf(0.1f);

    // ---- init: ring = r0 everywhere; zero pool scratch ----
    for (int e = tid; e < RING_FLOATS; e += NTHR)
        lds[e] = initial_cond[2 * ((e >> 1) & 127)];
    for (int e = tid; e < NREG * NSING; e += NTHR) { sw[e] = 0.f; smeta[e] = 0; }
    if (tid < NREG) cnt[tid] = 0;
    __syncthreads();

    // ================= per-role persistent state =================
    float w[16]; unsigned A[16];
    float2 pf[8];                                  // prefetched pair data
    float sW0=0.f, sW1=0.f, sW2=0.f;               // pooled singles (A only)
    unsigned sJ0=0, sJ1=0, sJ2=0;
    int sB0=0, sB1=0, sB2=0;
    float carry0 = 0.f, carry1 = 0.f;
    float c_cur=0.f, c0part=0.f;
    float xr=0.f, xV=0.f, eta=0.f, g0=0.f;
    float2 nz = make_float2(0.f,0.f);
    float bs=1.f, bf=1.f, bv=1.f, bq=1.f;

#pragma unroll
    for (int q = 0; q < 8; ++q) pf[q] = make_float2(0.f, 0.f);

    // ---- team setup (both teams; j-base and time-bias differ) ----
    {
        const int lane = tid & 63;
        const int rot  = (lane >> 2) & 15;         // 16 quads cover 16 residues
        const int jb   = isA ? 0 : 64;
        const int tb   = isA ? 1 : 2;              // B reads one time ahead
        float sAll = 0.f, sKeptEv = 0.f, sOdd0 = 0.f, sOdd1 = 0.f;
#pragma unroll
        for (int k = 0; k < 16; ++k) {
            const int j  = jb + ((h << 4) | ((k + rot) & 15));
            const float ww = Wt[i * NREG + j];
            int lg = lags[i * NREG + j];
            const float r0j = *(const float*)(histc + (j << 3));   // time0 = r0_j
            sAll = fmaf(ww, r0j, sAll);
            float wp = ww;
            if (lg <= 2) {                    // redistribute into region pool
                wp = 0.f;
                const int pos = atomicAdd(&cnt[i], 1);
                if (pos < NSING) {
                    sw[i * NSING + pos]    = ww;
                    smeta[i * NSING + pos] = (j << 3) | (lg - 1);
                }
                lg = 4;                       // safe addr for the dead slot
            }
            w[k] = wp;
            if (k & 1) {
                if ((k >> 1) & 1) sOdd1 = fmaf(wp, r0j, sOdd1);
                else              sOdd0 = fmaf(wp, r0j, sOdd0);
            } else {
                sKeptEv = fmaf(wp, r0j, sKeptEv);
            }
            // first read (consumed at s=k&1): pair start T0 = (k&1)+tb-lg
            const int Tb = (k & 1) + tb - lg + 260;        // positive, parity kept
            int A0 = (Tb * 1024) % (int)RING_BYTES + (j << 3);
            A0 -= 2048;                                     // pre-decrement
            if (A0 < 0) A0 += (int)RING_BYTES;
            A[k] = (unsigned)A0;
        }
        carry0 = sOdd0;
        carry1 = sOdd1;
        if (isA) {
            c0part = reduce4(sAll);          // A half of c(0), needs +bC0
            eta = region_pars[i];
            g0  = g[0];
            xr  = initial_cond[2 * i];
            xV  = initial_cond[2 * i + 1];
            nz  = *reinterpret_cast<const float2*>(&noise[(size_t)i * 2]);
        } else {
            const float full = reduce4(sAll);                       // c(0) half
            const float bulk = reduce4(sKeptEv + sOdd0 + sOdd1);    // lag>=3 r0 sum
            if (h == 0) { bC0[i] = full; bB[1][i] = bulk; }         // c(1) bulk-B
        }
        // prologue prefetch: parity-0 slots (consumed at step 0; all r0)
#pragma unroll
        for (int k = 0; k < 16; ++k) {
            if ((k & 1) == 0) {
                unsigned a2 = A[k] + 2048u;
                a2 = min(a2, a2 - RING_BYTES);
                A[k] = a2;
                pf[k >> 1] = *reinterpret_cast<const float2*>(histc + a2);
            }
        }
    }
    __syncthreads();   // pool + bC0/bB[1] visible

    if (isA) {
        const int b = i * NSING + h * 3;
        sW0 = sw[b];     sW1 = sw[b + 1]; sW2 = sw[b + 2];
        const int m0 = smeta[b], m1 = smeta[b + 1], m2 = smeta[b + 2];
        sJ0 = (unsigned)(m0 & ~7); sB0 = m0 & 1;
        sJ1 = (unsigned)(m1 & ~7); sB1 = m1 & 1;
        sJ2 = (unsigned)(m2 & ~7); sB2 = m2 & 1;
        c_cur = c0part + bC0[i];             // full c(0)
    }
    __syncthreads();   // everyone consumed prologue LDS before loop writes

    auto bstep = [&](float x) {
        const float pv1_ = pow3125(bv);
        const float e1  = fexp2_raw(L06 * frcp_raw(bf));
        const float d1s = x - RTS * bs - RTF * (bf - 1.f);
        const float d1f = bs;
        const float d1v = RTO * (bf - pv1_);
        const float d1q = RTO * (bf * (1.f - e1) * 2.5f - pv1_ * bq * frcp_raw(bv));
        const float s2v = bs + 0.01f * d1s;
        const float f2v = bf + 0.01f * d1f;
        const float v2v = bv + 0.01f * d1v;
        const float q2v = bq + 0.01f * d1q;
        const float pv2_ = pow3125(v2v);
        const float e2  = fexp2_raw(L06 * frcp_raw(f2v));
        const float d2s = x - RTS * s2v - RTF * (f2v - 1.f);
        const float d2f = s2v;
        const float d2v = RTO * (f2v - pv2_);
        const float d2q = RTO * (f2v * (1.f - e2) * 2.5f - pv2_ * q2v * frcp_raw(v2v));
        bs += 0.005f * (d1s + d2s);
        bf += 0.005f * (d1f + d2f);
        bv += 0.005f * (d1v + d2v);
        bq += 0.005f * (d1q + d2q);
    };

    auto stepBody = [&](auto PHC, int s) {
        constexpr int PH = decltype(PHC)::value;         // == s & 1
        const unsigned rowS = rowOf(s);                  // row of r(s)
        if (isA) {
            // prefetch next step's noise/stim (ride across barriers)
            const int sn = (s < NSTEP - 1) ? s + 1 : NSTEP - 1;
            const float2 nz_next =
                *reinterpret_cast<const float2*>(&noise[(size_t)(sn * NREG + i) * 2]);
            const float stim_cur = stimulus[s / 10];
            const unsigned rowSm1 = rowOf(s - 1);        // row of r(s-1)

            // post-barrier loads: 3 pooled singles + B's bulk float
            const unsigned ra0 = (sB0 ? rowSm1 : rowS) + sJ0;
            const unsigned ra1 = (sB1 ? rowSm1 : rowS) + sJ1;
            const unsigned ra2 = (sB2 ? rowSm1 : rowS) + sJ2;
            const float sv0 = *(const float*)(histc + ra0);
            const float sv1 = *(const float*)(histc + ra1);
            const float sv2 = *(const float*)(histc + ra2);
            const float bBv = bB[(s + 1) & 1][i];        // bulk-B of c(s+1)

            // consume prefetched pairs (pure-register fma tree)
            float an0 = carry0, an1 = carry1, ax0 = 0.f, ax1 = 0.f;
#pragma unroll
            for (int k = 0; k < 16; ++k) {
                if ((k & 1) == PH) {
                    const float2 v = pf[k >> 1];
                    if ((k >> 1) & 1) {
                        an1 = fmaf(w[k], v.x, an1);         // -> c(s+1)
                        ax1 = fmaf(w[k], v.y, ax1);         // -> c(s+2)
                    } else {
                        an0 = fmaf(w[k], v.x, an0);
                        ax0 = fmaf(w[k], v.y, ax0);
                    }
                }
            }
            an0 = fmaf(sW0, sv0, an0);
            an1 = fmaf(sW1, sv1, an1);
            an0 = fmaf(sW2, sv2, an0);

            const float c_next = reduce4(an0 + an1) + bBv;  // full c(s+1)

            // ---- MPR Heun (redundant in the 4 quad lanes) ----
            const float stim_i = (i == 0) ? stim_cur : 0.f;
            const float dw_r = DWS * nz.x;
            const float dw_V = DWS * nz.y;

            const float I1  = g0 * c_cur + stim_i;
            const float dr1 = ONE_PI + (2.0f * xr) * xV;
            const float p1  = PI_F * xr;
            const float dV1 = ((xV * xV + eta) + 15.0f * xr + I1) - p1 * p1;

            const float xir = fmaxf((xr + 0.1f * dr1) + dw_r, 0.f);
            const float xiV = (xV + 0.1f * dV1) + dw_V;

            const float I2  = g0 * c_next + stim_i;
            const float dr2 = ONE_PI + (2.0f * xir) * xiV;
            const float p2  = PI_F * xir;
            const float dV2 = ((xiV * xiV + eta) + 15.0f * xir + I2) - p2 * p2;

            const float nxr = fmaxf((xr + 0.05f * (dr1 + dr2)) + dw_r, 0.f);
            const float nxV = (xV + 0.05f * (dV1 + dV2)) + dw_V;

            if (h == 0) {
                const int X = s + 1;
                *(float*)(histc + (((unsigned)(X >> 1) % UNITS) * 2048u)
                                + ((X & 1) << 2) + (i << 3)) = nxr;
                *(float*)(histc + (((unsigned)((X - 1) >> 1) % UNITS) * 2048u) + 1024u
                                + (((X & 1) ^ 1) << 2) + (i << 3)) = nxr;
                *reinterpret_cast<float2*>(&out[(size_t)(s * NREG + i) * 2]) =
                    make_float2(nxr, nxV);
            }

            // refill for step s+1: LAST, drained by the barrier
#pragma unroll
            for (int k = 0; k < 16; ++k) {
                if ((k & 1) != PH) {
                    unsigned a2 = A[k] + 2048u;
                    a2 = min(a2, a2 - RING_BYTES);          // mod-65 wrap
                    A[k] = a2;
                    pf[k >> 1] = *reinterpret_cast<const float2*>(histc + a2);
                }
            }

            carry0 = ax0; carry1 = ax1;
            c_cur = c_next;
            xr = nxr; xV = nxV;
            nz = nz_next;
        } else {
            // ---- team B: bulk(s+2) partial + BOLD ----
            float an0 = carry0, an1 = carry1, ax0 = 0.f, ax1 = 0.f;
#pragma unroll
            for (int k = 0; k < 16; ++k) {
                if ((k & 1) == PH) {
                    const float2 v = pf[k >> 1];
                    if ((k >> 1) & 1) {
                        an1 = fmaf(w[k], v.x, an1);         // -> c(s+2)
                        ax1 = fmaf(w[k], v.y, ax1);         // -> c(s+3)
                    } else {
                        an0 = fmaf(w[k], v.x, an0);
                        ax0 = fmaf(w[k], v.y, ax0);
                    }
                }
            }
            const float bulkB = reduce4(an0 + an1);
            if (h == 0) {
                bB[s & 1][i] = bulkB;                       // for A at step s+1
                if (s > 0) bstep(*(const float*)(histc + rowS + (i << 3)));
            }
            // refill for step s+1: LAST
#pragma unroll
            for (int k = 0; k < 16; ++k) {
                if ((k & 1) != PH) {
                    unsigned a2 = A[k] + 2048u;
                    a2 = min(a2, a2 - RING_BYTES);
                    A[k] = a2;
                    pf[k >> 1] = *reinterpret_cast<const float2*>(histc + a2);
                }
            }
            carry0 = ax0; carry1 = ax1;
        }
        wg_barrier();
    };

    for (int sp = 0; sp < NSTEP / 2; ++sp) {
        stepBody(std::integral_constant<int,0>{}, 2 * sp);
        stepBody(std::integral_constant<int,1>{}, 2 * sp + 1);
    }

    // ---- epilogue: last BOLD input r(1000), then bold output ----
    if (!isA && h == 0) {
        bstep(*(const float*)(histc + rowOf(NSTEP) + (i << 3)));
        const float bold = 4.0f * (K1 * (1.f - bq) + K2 * (1.f - bq * frcp_raw(bv))
                                   + 0.5f * (1.f - bv));
        out[(size_t)NSTEP * NREG * 2 + i] = bold;
    }
}

extern "C" void kernel_launch(void* const* d_in, const int* in_sizes, int n_in,
                              void* d_out, int out_size, void* d_ws, size_t ws_size,
                              hipStream_t stream) {
    const float* region_pars  = (const float*)d_in[0];
    const float* Wt           = (const float*)d_in[1];
    const float* g            = (const float*)d_in[2];
    const float* stimulus     = (const float*)d_in[3];
    const float* noise        = (const float*)d_in[4];
    const float* initial_cond = (const float*)d_in[5];
    const int*   lags         = (const int*)d_in[6];
    // d_in[7] = ix_lag_from: always tile(arange(N)) -> implicit in our layout

    tvb_kernel<<<dim3(1), dim3(NTHR), 0, stream>>>(
        region_pars, Wt, g, stimulus, noise, initial_cond, lags, (float*)d_out);
}

// Round 16
// 632.022 us; speedup vs baseline: 1.3885x; 1.3885x over previous
//
#include <hip/hip_runtime.h>
#include <math.h>
#include <type_traits>

// TVB MPR simulation + BOLD, v16: v13 champion (635us) + ONE change:
// counted-drain step barrier. The two ring ds_writes must complete before
// s_barrier, but the 8 refill ds_read_b64s (issued after them) may ride
// across: DS ops complete in order, so `s_waitcnt lgkmcnt(8)` == "writes
// done, refills still in flight". Next step's pf[] consume re-waits via the
// compiler's own counted lgkmcnt, by which time the latency has drained
// under the barrier. Removes ~120-150 cyc of exposed refill latency per
// step from every wave's critical path (the LDS analog of T4 counted-vmcnt).
//
// Everything else is v13 verbatim:
// 640 threads = 10 waves:
//   tid 0..511  : gather+MPR, 4 threads/region, 32 term-slots each.
//     lag>=3 pairs: ds_read_b64 = (r(t), r(t+1)) prefetched one step ahead
//     into pf[16]; consume is a pure-register fma tree; refill issued LAST.
//     lag<=2 terms: pooled per REGION (12 slots, 3/lane), read post-barrier
//     from row s (lag1) or row s-1 (lag2).
//   tid 512..639: BOLD Heun chain on r(s), one step behind.
//   65-unit dual-copy pair ring (race-free single phase per step).

namespace {
constexpr int NREG  = 128;
constexpr int NSTEP = 1000;
constexpr int UNITS = 65;
constexpr unsigned RING_BYTES = UNITS * 2048u;      // 133120
constexpr int RING_FLOATS = (int)(RING_BYTES / 4);  // 33280
constexpr int NSING = 12;                           // pool slots per region

__device__ __forceinline__ float fsqrt_raw(float x){ float r; asm("v_sqrt_f32 %0, %1" : "=v"(r) : "v"(x)); return r; }
__device__ __forceinline__ float frcp_raw (float x){ float r; asm("v_rcp_f32 %0, %1" : "=v"(r) : "v"(x)); return r; }
__device__ __forceinline__ float fexp2_raw(float x){ float r; asm("v_exp_f32 %0, %1" : "=v"(r) : "v"(x)); return r; }

__device__ __forceinline__ float pow3125(float v) {
    float s1 = fsqrt_raw(v);
    float s2 = fsqrt_raw(s1);
    float s3 = fsqrt_raw(s2);
    return v * v * v * s3;
}

__device__ __forceinline__ float dpp_add_xor1(float x){
    int y = __builtin_amdgcn_mov_dpp(__float_as_int(x), 0xB1, 0xF, 0xF, true); // [1,0,3,2]
    return x + __int_as_float(y);
}
__device__ __forceinline__ float dpp_add_xor2(float x){
    int y = __builtin_amdgcn_mov_dpp(__float_as_int(x), 0x4E, 0xF, 0xF, true); // [2,3,0,1]
    return x + __int_as_float(y);
}

// full-drain barrier (prologue/epilogue)
__device__ __forceinline__ void wg_barrier() {
    asm volatile("s_waitcnt lgkmcnt(0)" ::: "memory");
    __builtin_amdgcn_s_barrier();
    asm volatile("" ::: "memory");
}

// counted-drain step barrier: waits the 2 ring writes (issued BEFORE the 8
// refill reads; DS completes in order) while the refills ride across.
__device__ __forceinline__ void wg_barrier_w8() {
    __builtin_amdgcn_sched_barrier(0);
    asm volatile("s_waitcnt lgkmcnt(8)" ::: "memory");
    __builtin_amdgcn_sched_barrier(0);
    __builtin_amdgcn_s_barrier();
    asm volatile("" ::: "memory");
}

// copyA dword byte-offset of time T on the 65-unit ring (valid T >= -260)
__device__ __forceinline__ unsigned rowOf(int T) {
    const unsigned Tb = (unsigned)(T + 260);        // parity-preserving bias
    return ((Tb >> 1) % UNITS) * 2048u + ((Tb & 1u) << 2);
}
} // namespace

__launch_bounds__(640, 2)
__global__ void tvb_kernel(const float* __restrict__ region_pars,  // (128,1)
                           const float* __restrict__ Wt,           // (128,128,1)
                           const float* __restrict__ g,            // (1,)
                           const float* __restrict__ stimulus,     // (100,1)
                           const float* __restrict__ noise,        // (100,10,128,2)
                           const float* __restrict__ initial_cond, // (128,2)
                           const int*   __restrict__ lags,         // (128,128)
                           float* __restrict__ out)                // rv(1000,128,2) ++ bold(128)
{
    __shared__ float lds[RING_FLOATS];       // 130 KB pair ring
    __shared__ float sw[NREG * NSING];       // pool: weights
    __shared__ int   smeta[NREG * NSING];    // pool: (j<<3)|(lag-1)
    __shared__ int   cnt[NREG];              // pool fill counters
    char* histc = (char*)lds;

    const int tid = (int)threadIdx.x;
    const bool isG = tid < 512;
    const int i  = tid >> 2;      // gather region
    const int h  = tid & 3;
    const int i3 = tid - 512;     // BOLD region

    // ---- constants ----
    constexpr float ONE_PI = (float)(1.0 / 3.14159265358979323846);
    constexpr float PI_F   = (float)3.14159265358979323846;
    constexpr float RTS    = (float)(1.0 / 0.65);
    constexpr float RTF    = (float)(1.0 / 0.41);
    constexpr float RTO    = (float)(1.0 / 0.98);
    constexpr float K1     = (float)(4.3 * 40.3 * 0.4 * 0.04);
    constexpr float K2     = (float)(0.5 * 25.0 * 0.4 * 0.04);
    constexpr float L06    = -0.7369655941662062f;                  // log2(0.6)
    const float DWS = 0.01f * sqrtf(0.1f);

    // ---- init: ring = r0 everywhere; zero pool scratch ----
    for (int e = tid; e < RING_FLOATS; e += 640)
        lds[e] = initial_cond[2 * ((e >> 1) & 127)];
    for (int e = tid; e < NREG * NSING; e += 640) { sw[e] = 0.f; smeta[e] = 0; }
    if (tid < NREG) cnt[tid] = 0;
    __syncthreads();

    // ================= per-role persistent state =================
    float w[32]; unsigned A[32];
    float2 pf[16];                                 // prefetched pair data
    float sW0=0.f, sW1=0.f, sW2=0.f;               // pooled singles (3/lane)
    unsigned sJ0=0, sJ1=0, sJ2=0;
    int sB0=0, sB1=0, sB2=0;
    float carry0 = 0.f, carry1 = 0.f, c_cur = 0.f;
    float xr=0.f, xV=0.f, eta=0.f, g0=0.f;
    float2 nz = make_float2(0.f,0.f);
    float bs=1.f, bf=1.f, bv=1.f, bq=1.f;

#pragma unroll
    for (int q = 0; q < 16; ++q) pf[q] = make_float2(0.f, 0.f);

    if (isG) {
        const int lane = tid & 63;
        const int rot  = (lane >> 2) + ((lane & 3) << 3);
        float sAll = 0.f, sOdd0 = 0.f, sOdd1 = 0.f;
#pragma unroll
        for (int k = 0; k < 32; ++k) {
            const int j  = (h << 5) | ((k + rot) & 31);
            const float ww = Wt[i * NREG + j];
            int lg = lags[i * NREG + j];
            const float r0j = *(const float*)(histc + (j << 3));   // time0 = r0_j
            sAll = fmaf(ww, r0j, sAll);
            float wp = ww;
            if (lg <= 2) {                    // redistribute into region pool
                wp = 0.f;
                const int pos = atomicAdd(&cnt[i], 1);
                if (pos < NSING) {
                    sw[i * NSING + pos]    = ww;
                    smeta[i * NSING + pos] = (j << 3) | (lg - 1);
                }
                lg = 4;                       // safe addr for the dead slot
            }
            w[k] = wp;
            if (k & 1) {
                if ((k >> 1) & 1) sOdd1 = fmaf(wp, r0j, sOdd1);
                else              sOdd0 = fmaf(wp, r0j, sOdd0);
            }
            // first read (consumed at s = k&1) targets pair starting T0 = (k&1)+1-lg
            const int Tb   = (k & 1) + 1 - lg + 260;       // positive, parity kept
            const int unit = (Tb >> 1) % UNITS;
            int A0 = unit * 2048 + (Tb & 1) * 1024 + (j << 3);
            A0 -= 2048;                                     // pre-decrement
            if (A0 < 0) A0 += (int)RING_BYTES;
            A[k] = (unsigned)A0;
        }
        carry0 = sOdd0;                      // odd slots' pending part of c(1)
        carry1 = sOdd1;
        sAll = dpp_add_xor1(sAll);
        sAll = dpp_add_xor2(sAll);
        c_cur = sAll;                        // c(0)
        eta = region_pars[i];
        g0  = g[0];
        xr  = initial_cond[2 * i];
        xV  = initial_cond[2 * i + 1];
        nz  = *reinterpret_cast<const float2*>(&noise[(size_t)i * 2]);

        // ---- prologue prefetch: step-0 due pairs (parity 0; all r0) ----
#pragma unroll
        for (int k = 0; k < 32; ++k) {
            if ((k & 1) == 0) {
                unsigned a2 = A[k] + 2048u;
                a2 = min(a2, a2 - RING_BYTES);
                A[k] = a2;
                pf[k >> 1] = *reinterpret_cast<const float2*>(histc + a2);
            }
        }
    }
    __syncthreads();   // pool fill complete; orders prologue reads vs writes

    // ---- load this lane's 3 pooled singles ----
    if (isG) {
        const int b = i * NSING + h * 3;
        sW0 = sw[b];     sW1 = sw[b + 1]; sW2 = sw[b + 2];
        const int m0 = smeta[b], m1 = smeta[b + 1], m2 = smeta[b + 2];
        sJ0 = (unsigned)(m0 & ~7); sB0 = m0 & 1;
        sJ1 = (unsigned)(m1 & ~7); sB1 = m1 & 1;
        sJ2 = (unsigned)(m2 & ~7); sB2 = m2 & 1;
    }

    auto bstep = [&](float x) {
        const float pv1_ = pow3125(bv);
        const float e1  = fexp2_raw(L06 * frcp_raw(bf));
        const float d1s = x - RTS * bs - RTF * (bf - 1.f);
        const float d1f = bs;
        const float d1v = RTO * (bf - pv1_);
        const float d1q = RTO * (bf * (1.f - e1) * 2.5f - pv1_ * bq * frcp_raw(bv));
        const float s2v = bs + 0.01f * d1s;
        const float f2v = bf + 0.01f * d1f;
        const float v2v = bv + 0.01f * d1v;
        const float q2v = bq + 0.01f * d1q;
        const float pv2_ = pow3125(v2v);
        const float e2  = fexp2_raw(L06 * frcp_raw(f2v));
        const float d2s = x - RTS * s2v - RTF * (f2v - 1.f);
        const float d2f = s2v;
        const float d2v = RTO * (f2v - pv2_);
        const float d2q = RTO * (f2v * (1.f - e2) * 2.5f - pv2_ * q2v * frcp_raw(v2v));
        bs += 0.005f * (d1s + d2s);
        bf += 0.005f * (d1f + d2f);
        bv += 0.005f * (d1v + d2v);
        bq += 0.005f * (d1q + d2q);
    };

    auto stepBody = [&](auto PHC, int s) {
        constexpr int PH = decltype(PHC)::value;         // == s & 1
        const unsigned rowS = rowOf(s);                  // row of r(s)
        if (isG) {
            // prefetch next step's noise/stim (ride across barriers)
            const int sn = (s < NSTEP - 1) ? s + 1 : NSTEP - 1;
            const float2 nz_next =
                *reinterpret_cast<const float2*>(&noise[(size_t)(sn * NREG + i) * 2]);
            const float stim_cur = stimulus[s / 10];
            const unsigned rowSm1 = rowOf(s - 1);        // row of r(s-1)

            // ---- pooled singles: the only post-barrier loads (3) ----
            const unsigned ra0 = (sB0 ? rowSm1 : rowS) + sJ0;
            const unsigned ra1 = (sB1 ? rowSm1 : rowS) + sJ1;
            const unsigned ra2 = (sB2 ? rowSm1 : rowS) + sJ2;
            const float sv0 = *(const float*)(histc + ra0);
            const float sv1 = *(const float*)(histc + ra1);
            const float sv2 = *(const float*)(histc + ra2);

            // ---- consume prefetched pairs: pure-register fma tree ----
            float an0 = carry0, an1 = carry1, ax0 = 0.f, ax1 = 0.f;
#pragma unroll
            for (int k = 0; k < 32; ++k) {
                if ((k & 1) == PH) {
                    const float2 v = pf[k >> 1];
                    if ((k >> 1) & 1) {
                        an1 = fmaf(w[k], v.x, an1);         // -> c(s+1)
                        ax1 = fmaf(w[k], v.y, ax1);         // -> c(s+2)
                    } else {
                        an0 = fmaf(w[k], v.x, an0);
                        ax0 = fmaf(w[k], v.y, ax0);
                    }
                }
            }
            // pooled singles contributions to c(s+1)
            an0 = fmaf(sW0, sv0, an0);
            an1 = fmaf(sW1, sv1, an1);
            an0 = fmaf(sW2, sv2, an0);

            float anow = an0 + an1;
            anow = dpp_add_xor1(anow);
            anow = dpp_add_xor2(anow);
            const float c_next = anow;                      // c(s+1)

            // ---- MPR Heun (redundant in all 4 lanes of the quad) ----
            const float stim_i = (i == 0) ? stim_cur : 0.f;
            const float dw_r = DWS * nz.x;
            const float dw_V = DWS * nz.y;

            const float I1  = g0 * c_cur + stim_i;
            const float dr1 = ONE_PI + (2.0f * xr) * xV;
            const float p1  = PI_F * xr;
            const float dV1 = ((xV * xV + eta) + 15.0f * xr + I1) - p1 * p1;

            const float xir = fmaxf((xr + 0.1f * dr1) + dw_r, 0.f);
            const float xiV = (xV + 0.1f * dV1) + dw_V;

            const float I2  = g0 * c_next + stim_i;
            const float dr2 = ONE_PI + (2.0f * xir) * xiV;
            const float p2  = PI_F * xir;
            const float dV2 = ((xiV * xiV + eta) + 15.0f * xir + I2) - p2 * p2;

            const float nxr = fmaxf((xr + 0.05f * (dr1 + dr2)) + dw_r, 0.f);
            const float nxV = (xV + 0.05f * (dV1 + dV2)) + dw_V;

            if ((tid & 3) == 0) {
                const int X = s + 1;
                // copyA: unit (X>>1)%65, dword X&1
                *(float*)(histc + (((unsigned)(X >> 1) % UNITS) * 2048u)
                                + ((X & 1) << 2) + (i << 3)) = nxr;
                // copyB: unit ((X-1)>>1)%65, +1024, dword (X&1)^1
                *(float*)(histc + (((unsigned)((X - 1) >> 1) % UNITS) * 2048u) + 1024u
                                + (((X & 1) ^ 1) << 2) + (i << 3)) = nxr;
                *reinterpret_cast<float2*>(&out[(size_t)(s * NREG + i) * 2]) =
                    make_float2(nxr, nxV);
            }

            // ---- refill for step s+1: LAST; rides across the counted barrier ----
#pragma unroll
            for (int k = 0; k < 32; ++k) {
                if ((k & 1) != PH) {
                    unsigned a2 = A[k] + 2048u;
                    a2 = min(a2, a2 - RING_BYTES);          // mod-65 wrap
                    A[k] = a2;
                    pf[k >> 1] = *reinterpret_cast<const float2*>(histc + a2);
                }
            }

            carry0 = ax0; carry1 = ax1;
            c_cur = c_next;
            xr = nxr; xV = nxV;
            nz = nz_next;
        } else {
            // ---- BOLD: consume r(s) (written at step s-1) ----
            if (s > 0) bstep(*(const float*)(histc + rowS + (i3 << 3)));
        }
        // counted drain: ring writes complete (issued before the 8 refills;
        // DS is in-order), refill reads stay outstanding across the barrier.
        wg_barrier_w8();
    };

    for (int sp = 0; sp < NSTEP / 2; ++sp) {
        stepBody(std::integral_constant<int,0>{}, 2 * sp);
        stepBody(std::integral_constant<int,1>{}, 2 * sp + 1);
    }

    // ---- epilogue: last BOLD input r(1000), then bold output ----
    if (!isG) {
        bstep(*(const float*)(histc + rowOf(NSTEP) + (i3 << 3)));
        const float bold = 4.0f * (K1 * (1.f - bq) + K2 * (1.f - bq * frcp_raw(bv))
                                   + 0.5f * (1.f - bv));
        out[(size_t)NSTEP * NREG * 2 + i3] = bold;
    }
}

extern "C" void kernel_launch(void* const* d_in, const int* in_sizes, int n_in,
                              void* d_out, int out_size, void* d_ws, size_t ws_size,
                              hipStream_t stream) {
    const float* region_pars  = (const float*)d_in[0];
    const float* Wt           = (const float*)d_in[1];
    const float* g            = (const float*)d_in[2];
    const float* stimulus     = (const float*)d_in[3];
    const float* noise        = (const float*)d_in[4];
    const float* initial_cond = (const float*)d_in[5];
    const int*   lags         = (const int*)d_in[6];
    // d_in[7] = ix_lag_from: always tile(arange(N)) -> implicit in our layout

    tvb_kernel<<<dim3(1), dim3(640), 0, stream>>>(
        region_pars, Wt, g, stimulus, noise, initial_cond, lags, (float*)d_out);
}